// Round 1
// 411.303 us; speedup vs baseline: 1.5995x; 1.5995x over previous
//
#include <hip/hip_runtime.h>
#include <hip/hip_bf16.h>

#define EPS 1e-9f
#define LN_EPS 1e-5f

// ---------- helpers ----------
__device__ __forceinline__ float lo16(unsigned p) { return __uint_as_float(p << 16); }
__device__ __forceinline__ float hi16(unsigned p) { return __uint_as_float(p & 0xffff0000u); }
__device__ __forceinline__ unsigned f2b(float f) {
    unsigned u = __float_as_uint(f);
    return (u + 0x7fffu + ((u >> 16) & 1u)) >> 16;  // round-to-nearest-even
}
__device__ __forceinline__ float wred(float v) {
    #pragma unroll
    for (int m = 32; m >= 1; m >>= 1) v += __shfl_xor(v, m);
    return v;
}
// edge_index element i (tgt offset already applied by caller), robust to int32/int64
__device__ __forceinline__ int eidx(const int* ei, int i, int i64) {
    return i64 ? ei[2 * i] : ei[i];   // little-endian: low dword of int64
}
__device__ __forceinline__ float ldw(const float* fp, const __hip_bfloat16* hp, int i, int f32) {
    return f32 ? fp[i] : __bfloat162float(hp[i]);
}

// ---------- K0: dtype probe (1 wave). flags[0]=1 if floats are fp32; flags[1]=1 if idx int64 ----------
__global__ void probe_kernel(const unsigned* __restrict__ xb, const int* __restrict__ ei,
                             int* __restrict__ flags) {
    int lane = threadIdx.x & 63;
    unsigned d = xb[lane * 97];
    unsigned ex = (d >> 7) & 0xFFu;              // bf16-packed: low-half bf16 exponent field
    unsigned long long m1 = __ballot(ex >= 110u && ex <= 135u);
    int hi = ei[2 * lane + 1];                   // int64: odd dwords are all zero
    unsigned long long m2 = __ballot(hi == 0);
    if (lane == 0) {
        flags[0] = (__popcll(m1) > 32) ? 0 : 1;  // many bf16-exponent hits -> packed bf16
        flags[1] = (__popcll(m2) > 32) ? 1 : 0;
    }
}

// ---------- K2: per-edge softmax denominator + degree count ----------
__global__ void edge_denom_count(const int* __restrict__ ei, const float* __restrict__ ewf,
                                 const __hip_bfloat16* __restrict__ ewh,
                                 float* __restrict__ denom, int* __restrict__ count,
                                 const int* __restrict__ flags, int E) {
    int e = blockIdx.x * 256 + threadIdx.x;
    if (e >= E) return;
    int f32 = flags[0], i64 = flags[1];
    int t = eidx(ei, E + e, i64);
    float w = ldw(ewf, ewh, e, f32);
    atomicAdd(&denom[t], expf(w));
    atomicAdd(&count[t], 1);
}

// ---------- K3: single-block exclusive scan over counts -> offsets, cursor ----------
__global__ void scan_kernel(const int* __restrict__ count, int* __restrict__ offsets,
                            int* __restrict__ cursor, int N) {
    __shared__ int wsum[16];
    __shared__ int s_carry;
    int tid = threadIdx.x, lane = tid & 63, w = tid >> 6;
    if (tid == 0) s_carry = 0;
    __syncthreads();
    for (int base = 0; base < N; base += 1024) {
        int i = base + tid;
        int v = (i < N) ? count[i] : 0;
        int incl = v;
        #pragma unroll
        for (int off = 1; off < 64; off <<= 1) {
            int t = __shfl_up(incl, off);
            if (lane >= off) incl += t;
        }
        if (lane == 63) wsum[w] = incl;
        __syncthreads();
        int wpre = 0, tot = 0;
        #pragma unroll
        for (int j = 0; j < 16; ++j) { int s = wsum[j]; if (j < w) wpre += s; tot += s; }
        int excl = s_carry + wpre + incl - v;
        if (i < N) { offsets[i] = excl; cursor[i] = excl; }
        __syncthreads();
        if (tid == 0) s_carry += tot;
        __syncthreads();
    }
    if (threadIdx.x == 0) offsets[N] = s_carry;
}

// ---------- K4: scatter edges into CSR buckets with precomputed alpha ----------
__global__ void edge_scatter(const int* __restrict__ ei, const float* __restrict__ ewf,
                             const __hip_bfloat16* __restrict__ ewh,
                             const float* __restrict__ denom, int* __restrict__ cursor,
                             int* __restrict__ csr_src, float* __restrict__ csr_alpha,
                             const int* __restrict__ flags, int E) {
    int e = blockIdx.x * 256 + threadIdx.x;
    if (e >= E) return;
    int f32 = flags[0], i64 = flags[1];
    int t = eidx(ei, E + e, i64);
    int s = eidx(ei, e, i64);
    float w = ldw(ewf, ewh, e, f32);
    float al = expf(w) / denom[t];
    int pos = atomicAdd(&cursor[t], 1);
    csr_src[pos] = s;
    csr_alpha[pos] = al;
}

// ---------- K5: one wave per target node; weighted sum of x[src], proj-normalize ----------
__global__ void aggregate(const unsigned* __restrict__ xb, const float2* __restrict__ xf,
                          const int* __restrict__ offsets, const int* __restrict__ csr_src,
                          const float* __restrict__ csr_alpha, float2* __restrict__ agg,
                          const int* __restrict__ flags, int N) {
    int node = blockIdx.x * 4 + (threadIdx.x >> 6);
    if (node >= N) return;
    int lane = threadIdx.x & 63;
    int f32 = flags[0];
    float a0 = 0.f, a1 = 0.f;
    int beg = offsets[node], end = offsets[node + 1];
    if (f32) {
        for (int j = beg; j < end; ++j) {
            int s = csr_src[j];
            float al = csr_alpha[j];
            float2 v = xf[s * 64 + lane];
            a0 += al * v.x; a1 += al * v.y;
        }
    } else {
        for (int j = beg; j < end; ++j) {
            int s = csr_src[j];
            float al = csr_alpha[j];
            unsigned p = xb[s * 64 + lane];
            a0 += al * lo16(p); a1 += al * hi16(p);
        }
    }
    float ss = wred(a0 * a0 + a1 * a1);
    float inv = 1.f / (sqrtf(ss) + EPS);
    agg[node * 64 + lane] = make_float2(a0 * inv, a1 * inv);
}

// ---------- K6: fused dual matvec + combine + proj-normalize + layernorm ----------
// v2: 32 nodes per block staged in LDS; each wave computes 8 nodes against each
// weight row it loads -> 8x less weight L2 traffic, zero shuffles in main loop.
// LDS layout: s_xa4[n][u] = float4(x[n][2u], agg[n][2u], x[n][2u+1], agg[n][2u+1])
// read as float2 pairs {x[n][k], agg[n][k]} -- wave-uniform address = broadcast.
__global__ __launch_bounds__(256) void fused_out(
                          const unsigned* __restrict__ xb, const float2* __restrict__ xf,
                          const float2* __restrict__ agg,
                          const unsigned* __restrict__ Wsb, const float2* __restrict__ Wsf,
                          const unsigned* __restrict__ Wnb, const float2* __restrict__ Wnf,
                          const float* __restrict__ bsf, const __hip_bfloat16* __restrict__ bsh,
                          const float* __restrict__ bnf, const __hip_bfloat16* __restrict__ bnh,
                          const float* __restrict__ gf, const __hip_bfloat16* __restrict__ gh,
                          const float* __restrict__ tf, const __hip_bfloat16* __restrict__ th,
                          unsigned* __restrict__ outb, float2* __restrict__ outf,
                          const int* __restrict__ flags, int N) {
    __shared__ float4 s_xa4[32 * 64];           // 32 KB
    int node0 = blockIdx.x * 32;
    int tid = threadIdx.x;
    int lane = tid & 63;
    int w = tid >> 6;
    int f32 = flags[0];

    // ---- stage x + agg for 32 nodes (coalesced global, one ds_write_b128/iter) ----
    for (int i = tid; i < 32 * 64; i += 256) {
        int n = i >> 6, u = i & 63;
        int node = node0 + n;
        float2 xv = make_float2(0.f, 0.f), av = make_float2(0.f, 0.f);
        if (node < N) {
            if (f32) xv = xf[node * 64 + u];
            else { unsigned p = xb[node * 64 + u]; xv = make_float2(lo16(p), hi16(p)); }
            av = agg[node * 64 + u];
        }
        s_xa4[n * 64 + u] = make_float4(xv.x, av.x, xv.y, av.y);
    }
    __syncthreads();

    int nbase = w * 8;                           // this wave's 8 nodes
    const float2* sxa = reinterpret_cast<const float2*>(s_xa4) + nbase * 128;

    float acc0[8], acc1[8];
    #pragma unroll
    for (int j = 0; j < 8; ++j) { acc0[j] = 0.f; acc1[j] = 0.f; }

    if (f32) {
        #pragma unroll 4
        for (int k = 0; k < 128; ++k) {
            float2 ws = Wsf[k * 64 + lane];      // (Ws[k][2*lane], Ws[k][2*lane+1])
            float2 wn = Wnf[k * 64 + lane];
            #pragma unroll
            for (int j = 0; j < 8; ++j) {
                float2 v = sxa[j * 128 + k];     // broadcast: {x[n][k], agg[n][k]}
                acc0[j] += v.x * ws.x + v.y * wn.x;
                acc1[j] += v.x * ws.y + v.y * wn.y;
            }
        }
    } else {
        #pragma unroll 4
        for (int k = 0; k < 128; ++k) {
            unsigned wsp = Wsb[k * 64 + lane];
            unsigned wnp = Wnb[k * 64 + lane];
            float wsx = lo16(wsp), wsy = hi16(wsp);
            float wnx = lo16(wnp), wny = hi16(wnp);
            #pragma unroll
            for (int j = 0; j < 8; ++j) {
                float2 v = sxa[j * 128 + k];
                acc0[j] += v.x * wsx + v.y * wnx;
                acc1[j] += v.x * wsy + v.y * wny;
            }
        }
    }

    // ---- epilogue: combine + proj-normalize + layernorm, per node ----
    int f0 = 2 * lane, f1 = f0 + 1;
    float bsum0 = ldw(bsf, bsh, f0, f32) + ldw(bnf, bnh, f0, f32);
    float bsum1 = ldw(bsf, bsh, f1, f32) + ldw(bnf, bnh, f1, f32);
    float g0 = ldw(gf, gh, f0, f32), g1 = ldw(gf, gh, f1, f32);
    float t0 = ldw(tf, th, f0, f32), t1 = ldw(tf, th, f1, f32);

    #pragma unroll
    for (int j = 0; j < 8; ++j) {
        int node = node0 + nbase + j;
        float c0 = 0.5f * (acc0[j] + bsum0);
        float c1 = 0.5f * (acc1[j] + bsum1);
        float ss = wred(c0 * c0 + c1 * c1);
        float inv = 1.f / (sqrtf(ss) + EPS);
        c0 *= inv; c1 *= inv;
        float mean = wred(c0 + c1) * (1.f / 128.f);
        float d0 = c0 - mean, d1 = c1 - mean;
        float var = wred(d0 * d0 + d1 * d1) * (1.f / 128.f);
        float rstd = 1.f / sqrtf(var + LN_EPS);
        float o0 = d0 * rstd * g0 + t0;
        float o1 = d1 * rstd * g1 + t1;
        if (node < N) {
            int idx = node * 64 + lane;
            if (f32) outf[idx] = make_float2(o0, o1);
            else     outb[idx] = f2b(o0) | (f2b(o1) << 16);
        }
    }
}

extern "C" void kernel_launch(void* const* d_in, const int* in_sizes, int n_in,
                              void* d_out, int out_size, void* d_ws, size_t ws_size,
                              hipStream_t stream) {
    int N = in_sizes[0] / 128;
    int E = in_sizes[1] / 2;
    const int* ei = (const int*)d_in[1];

    char* p = (char*)d_ws;
    int* flags = (int*)p;              p += 16;
    float* denom = (float*)p;          p += (size_t)N * 4;
    int* count = (int*)p;              p += (size_t)N * 4;
    int* offsets = (int*)p;            p += (size_t)(N + 4) * 4;  // +4 keeps 16B alignment
    int* cursor = (int*)p;             p += (size_t)N * 4;
    int* csr_src = (int*)p;            p += (size_t)E * 4;
    float* csr_alpha = (float*)p;      p += (size_t)E * 4;
    float2* agg = (float2*)p;          // N*64 float2 = 25.6 MB

    // zero flags + denom + count (contiguous at start of ws)
    hipMemsetAsync(d_ws, 0, 16 + (size_t)N * 8, stream);

    int eb = (E + 255) / 256;
    int nb = (N + 3) / 4;
    int nb32 = (N + 31) / 32;
    probe_kernel<<<1, 64, 0, stream>>>((const unsigned*)d_in[0], ei, flags);
    edge_denom_count<<<eb, 256, 0, stream>>>(ei, (const float*)d_in[2], (const __hip_bfloat16*)d_in[2],
                                             denom, count, flags, E);
    scan_kernel<<<1, 1024, 0, stream>>>(count, offsets, cursor, N);
    edge_scatter<<<eb, 256, 0, stream>>>(ei, (const float*)d_in[2], (const __hip_bfloat16*)d_in[2],
                                         denom, cursor, csr_src, csr_alpha, flags, E);
    aggregate<<<nb, 256, 0, stream>>>((const unsigned*)d_in[0], (const float2*)d_in[0],
                                      offsets, csr_src, csr_alpha, agg, flags, N);
    fused_out<<<nb32, 256, 0, stream>>>((const unsigned*)d_in[0], (const float2*)d_in[0], agg,
                                      (const unsigned*)d_in[3], (const float2*)d_in[3],
                                      (const unsigned*)d_in[5], (const float2*)d_in[5],
                                      (const float*)d_in[4], (const __hip_bfloat16*)d_in[4],
                                      (const float*)d_in[6], (const __hip_bfloat16*)d_in[6],
                                      (const float*)d_in[7], (const __hip_bfloat16*)d_in[7],
                                      (const float*)d_in[8], (const __hip_bfloat16*)d_in[8],
                                      (unsigned*)d_out, (float2*)d_out, flags, N);
}

// Round 2
// 285.515 us; speedup vs baseline: 2.3043x; 1.4406x over previous
//
#include <hip/hip_runtime.h>
#include <hip/hip_bf16.h>

#define EPS 1e-9f
#define LN_EPS 1e-5f

typedef __attribute__((ext_vector_type(8))) short bf16x8;
typedef __attribute__((ext_vector_type(4))) float f32x4;

// ---------- helpers ----------
__device__ __forceinline__ float lo16(unsigned p) { return __uint_as_float(p << 16); }
__device__ __forceinline__ float hi16(unsigned p) { return __uint_as_float(p & 0xffff0000u); }
__device__ __forceinline__ unsigned f2b(float f) {
    unsigned u = __float_as_uint(f);
    return (u + 0x7fffu + ((u >> 16) & 1u)) >> 16;  // round-to-nearest-even
}
__device__ __forceinline__ int eidx(const int* ei, int i, int i64) {
    return i64 ? ei[2 * i] : ei[i];   // little-endian: low dword of int64
}
__device__ __forceinline__ float ldw(const float* fp, const __hip_bfloat16* hp, int i, int f32) {
    return f32 ? fp[i] : __bfloat162float(hp[i]);
}

// ---------- K0: dtype probe (1 wave). flags[0]=1 if floats are fp32; flags[1]=1 if idx int64 ----------
__global__ void probe_kernel(const unsigned* __restrict__ xb, const int* __restrict__ ei,
                             int* __restrict__ flags) {
    int lane = threadIdx.x & 63;
    unsigned d = xb[lane * 97];
    unsigned ex = (d >> 7) & 0xFFu;              // bf16-packed: low-half bf16 exponent field
    unsigned long long m1 = __ballot(ex >= 110u && ex <= 135u);
    int hi = ei[2 * lane + 1];                   // int64: odd dwords are all zero
    unsigned long long m2 = __ballot(hi == 0);
    if (lane == 0) {
        flags[0] = (__popcll(m1) > 32) ? 0 : 1;  // many bf16-exponent hits -> packed bf16
        flags[1] = (__popcll(m2) > 32) ? 1 : 0;
    }
}

// ---------- K1a: convert fp32 x -> packed bf16 copy (no-op in bf16 mode) ----------
__global__ void cvt_x(const float4* __restrict__ xf4, uint2* __restrict__ xcvt2,
                      const int* __restrict__ flags, int n4) {
    if (!flags[0]) return;
    int i = blockIdx.x * 256 + threadIdx.x;
    if (i >= n4) return;
    float4 v = xf4[i];
    xcvt2[i] = make_uint2(f2b(v.x) | (f2b(v.y) << 16), f2b(v.z) | (f2b(v.w) << 16));
}

// ---------- K1b: build Wt[f][k] bf16, k = 0..255 (Ws rows then Wn rows), row-major [128][256] ----------
__global__ void transpose_w(const unsigned* __restrict__ Wsb, const float* __restrict__ Wsf,
                            const unsigned* __restrict__ Wnb, const float* __restrict__ Wnf,
                            unsigned* __restrict__ wt, const int* __restrict__ flags) {
    int tid = blockIdx.x * 256 + threadIdx.x;    // 16384 threads: f = tid>>7, k-pair = tid&127
    int f = tid >> 7, k2 = tid & 127;
    int k2l = k2 & 63;
    unsigned out;
    if (flags[0]) {
        const float* W = (k2 < 64) ? Wsf : Wnf;
        float lo = W[(2 * k2l) * 128 + f], hi = W[(2 * k2l + 1) * 128 + f];
        out = f2b(lo) | (f2b(hi) << 16);
    } else {
        const unsigned* W = (k2 < 64) ? Wsb : Wnb;
        unsigned lo = W[(2 * k2l) * 64 + (f >> 1)];
        unsigned hi = W[(2 * k2l + 1) * 64 + (f >> 1)];
        unsigned a = (f & 1) ? (lo >> 16) : (lo & 0xffffu);
        unsigned b = (f & 1) ? (hi & 0xffff0000u) : (hi << 16);
        out = a | b;
    }
    wt[tid] = out;
}

// ---------- K2: per-target degree count (softmax denom cancels in proj-normalize -> dropped) ----------
__global__ void edge_count(const int* __restrict__ ei, int* __restrict__ count,
                           const int* __restrict__ flags, int E) {
    int e = blockIdx.x * 256 + threadIdx.x;
    if (e >= E) return;
    int t = eidx(ei, E + e, flags[1]);
    atomicAdd(&count[t], 1);
}

// ---------- K3: single-block exclusive scan, 4 elems/thread (13 iters for N=50k) ----------
__global__ void scan_kernel(const int* __restrict__ count, int* __restrict__ offsets,
                            int* __restrict__ cursor, int N) {
    __shared__ int wsum[16];
    __shared__ int s_carry;
    int tid = threadIdx.x, lane = tid & 63, w = tid >> 6;
    if (tid == 0) s_carry = 0;
    __syncthreads();
    for (int base = 0; base < N; base += 4096) {
        int i0 = base + tid * 4;
        int4 v;
        if (i0 + 3 < N) v = *(const int4*)(count + i0);
        else {
            v.x = (i0     < N) ? count[i0]     : 0;
            v.y = (i0 + 1 < N) ? count[i0 + 1] : 0;
            v.z = (i0 + 2 < N) ? count[i0 + 2] : 0;
            v.w = (i0 + 3 < N) ? count[i0 + 3] : 0;
        }
        int s = v.x + v.y + v.z + v.w;
        int incl = s;
        #pragma unroll
        for (int off = 1; off < 64; off <<= 1) {
            int t = __shfl_up(incl, off);
            if (lane >= off) incl += t;
        }
        if (lane == 63) wsum[w] = incl;
        __syncthreads();
        int wpre = 0, tot = 0;
        #pragma unroll
        for (int j = 0; j < 16; ++j) { int sj = wsum[j]; if (j < w) wpre += sj; tot += sj; }
        int o0 = s_carry + wpre + incl - s;
        int o1 = o0 + v.x, o2 = o1 + v.y, o3 = o2 + v.z;
        if (i0 + 3 < N) {
            *(int4*)(offsets + i0) = make_int4(o0, o1, o2, o3);
            *(int4*)(cursor + i0)  = make_int4(o0, o1, o2, o3);
        } else {
            if (i0     < N) { offsets[i0]     = o0; cursor[i0]     = o0; }
            if (i0 + 1 < N) { offsets[i0 + 1] = o1; cursor[i0 + 1] = o1; }
            if (i0 + 2 < N) { offsets[i0 + 2] = o2; cursor[i0 + 2] = o2; }
        }
        __syncthreads();
        if (tid == 0) s_carry += tot;
        __syncthreads();
    }
    if (threadIdx.x == 0) offsets[N] = s_carry;
}

// ---------- K4: scatter edges into CSR buckets; alpha = exp(w) (unnormalized, norm cancels) ----------
__global__ void edge_scatter(const int* __restrict__ ei, const float* __restrict__ ewf,
                             const __hip_bfloat16* __restrict__ ewh,
                             int* __restrict__ cursor,
                             int* __restrict__ csr_src, float* __restrict__ csr_alpha,
                             const int* __restrict__ flags, int E) {
    int e = blockIdx.x * 256 + threadIdx.x;
    if (e >= E) return;
    int f32 = flags[0], i64 = flags[1];
    int t = eidx(ei, E + e, i64);
    int s = eidx(ei, e, i64);
    float w = ldw(ewf, ewh, e, f32);
    float al = expf(w);
    int pos = atomicAdd(&cursor[t], 1);
    csr_src[pos] = s;
    csr_alpha[pos] = al;
}

// ---------- K5: one wave per target node; weighted sum of bf16 x[src], proj-normalize, bf16 out ----------
__global__ void aggregate(const unsigned* __restrict__ xb, const unsigned* __restrict__ xcvt,
                          const int* __restrict__ offsets, const int* __restrict__ csr_src,
                          const float* __restrict__ csr_alpha, unsigned* __restrict__ aggb,
                          const int* __restrict__ flags, int N) {
    int node = blockIdx.x * 4 + (threadIdx.x >> 6);
    if (node >= N) return;
    int lane = threadIdx.x & 63;
    const unsigned* xs = flags[0] ? xcvt : xb;   // always gather bf16 (half traffic)
    float a0 = 0.f, a1 = 0.f;
    int beg = offsets[node], end = offsets[node + 1];
    for (int j = beg; j < end; ++j) {
        int s = csr_src[j];
        float al = csr_alpha[j];
        unsigned p = xs[s * 64 + lane];
        a0 += al * lo16(p); a1 += al * hi16(p);
    }
    float ss = a0 * a0 + a1 * a1;
    #pragma unroll
    for (int m = 32; m >= 1; m >>= 1) ss += __shfl_xor(ss, m);
    float inv = 1.f / (sqrtf(ss) + EPS);
    aggb[node * 64 + lane] = f2b(a0 * inv) | (f2b(a1 * inv) << 16);
}

// ---------- K6: MFMA fused: C = 0.5*([x|agg] @ [Ws;Wn] + bs + bn) -> proj-norm -> LN ----------
// 64 nodes/block, 4 waves x 16 nodes. A = [x|agg] bf16 staged in XOR-swizzled LDS.
// B = Wt[f][k] bf16 from global (L1/L2 resident, 64 KB total).
// mfma_f32_16x16x32_bf16: A row = lane&15, k = (lane>>4)*8 + i (contiguous 8);
//                         C/D: col = lane&15, row = (lane>>4)*4 + reg  [learn_hip m89].
__global__ __launch_bounds__(256) void fused_mfma(
    const unsigned* __restrict__ xb, const unsigned* __restrict__ xcvt,
    const unsigned* __restrict__ aggb, const uint4* __restrict__ wt4,
    const float* __restrict__ bsf, const __hip_bfloat16* __restrict__ bsh,
    const float* __restrict__ bnf, const __hip_bfloat16* __restrict__ bnh,
    const float* __restrict__ gf, const __hip_bfloat16* __restrict__ gh,
    const float* __restrict__ tf, const __hip_bfloat16* __restrict__ th,
    float* __restrict__ outf, unsigned* __restrict__ outb,
    const int* __restrict__ flags, int N)
{
    __shared__ uint4 sA[2048];                   // 64 rows x 32 chunks of 16B = 32 KB
    int f32 = flags[0];
    const uint4* xs4 = (const uint4*)(f32 ? xcvt : xb);
    const uint4* ag4 = (const uint4*)aggb;
    int tid = threadIdx.x;
    int node0 = blockIdx.x * 64;

    // stage A: row r = [x bf16 (chunks 0-15) | agg bf16 (chunks 16-31)], XOR-swizzled
    #pragma unroll
    for (int i = 0; i < 8; ++i) {
        int ci = i * 256 + tid;
        int r = ci >> 5, c = ci & 31;
        int node = node0 + r;
        uint4 v = make_uint4(0, 0, 0, 0);
        if (node < N) v = (c < 16) ? xs4[node * 16 + c] : ag4[node * 16 + (c - 16)];
        sA[r * 32 + (c ^ (r & 15))] = v;
    }
    __syncthreads();

    int lane = tid & 63, w = tid >> 6, g = lane >> 4, c16 = lane & 15;
    int rloc = w * 16 + c16;                     // A row this lane reads

    f32x4 acc[8];
    #pragma unroll
    for (int t = 0; t < 8; ++t) acc[t] = (f32x4){0.f, 0.f, 0.f, 0.f};

    #pragma unroll
    for (int kk = 0; kk < 8; ++kk) {             // K = 256 in steps of 32
        uint4 av = sA[rloc * 32 + ((kk * 4 + g) ^ c16)];
        bf16x8 a = __builtin_bit_cast(bf16x8, av);
        #pragma unroll
        for (int t = 0; t < 8; ++t) {            // 8 feature tiles of 16
            uint4 bv = wt4[(t * 16 + c16) * 32 + kk * 4 + g];
            bf16x8 b = __builtin_bit_cast(bf16x8, bv);
            acc[t] = __builtin_amdgcn_mfma_f32_16x16x32_bf16(a, b, acc[t], 0, 0, 0);
        }
    }

    // per-lane feature params (features f = t*16 + c16)
    float bsum[8], gam[8], bet[8];
    #pragma unroll
    for (int t = 0; t < 8; ++t) {
        int f = t * 16 + c16;
        bsum[t] = ldw(bsf, bsh, f, f32) + ldw(bnf, bnh, f, f32);
        gam[t]  = ldw(gf, gh, f, f32);
        bet[t]  = ldw(tf, th, f, f32);
    }

    // epilogue: per node (4 per lane, one per acc reg), reduce over 16-lane group
    #pragma unroll
    for (int reg = 0; reg < 4; ++reg) {
        int node = node0 + w * 16 + g * 4 + reg;
        float cv[8], s1 = 0.f, s2 = 0.f;
        #pragma unroll
        for (int t = 0; t < 8; ++t) {
            float c_ = 0.5f * (acc[t][reg] + bsum[t]);
            cv[t] = c_; s1 += c_; s2 += c_ * c_;
        }
        #pragma unroll
        for (int m = 1; m < 16; m <<= 1) { s1 += __shfl_xor(s1, m); s2 += __shfl_xor(s2, m); }
        float inv  = 1.f / (sqrtf(s2) + EPS);
        float mean = s1 * inv * (1.f / 128.f);
        float var  = s2 * inv * inv * (1.f / 128.f) - mean * mean;
        float rstd = 1.f / sqrtf(var + LN_EPS);
        if (f32) {
            if (node < N) {
                #pragma unroll
                for (int t = 0; t < 8; ++t) {
                    float o = (cv[t] * inv - mean) * rstd * gam[t] + bet[t];
                    outf[(size_t)node * 128 + t * 16 + c16] = o;
                }
            }
        } else {
            #pragma unroll
            for (int t = 0; t < 8; ++t) {
                float o = (cv[t] * inv - mean) * rstd * gam[t] + bet[t];
                float po = __shfl_xor(o, 1);
                if (!(c16 & 1) && node < N)
                    outb[node * 64 + t * 8 + (c16 >> 1)] = f2b(o) | (f2b(po) << 16);
            }
        }
    }
}

static inline size_t rup16(size_t x) { return (x + 15) & ~(size_t)15; }

extern "C" void kernel_launch(void* const* d_in, const int* in_sizes, int n_in,
                              void* d_out, int out_size, void* d_ws, size_t ws_size,
                              hipStream_t stream) {
    int N = in_sizes[0] / 128;
    int E = in_sizes[1] / 2;
    const int* ei = (const int*)d_in[1];

    char* p = (char*)d_ws;
    int* flags = (int*)p;              p += 16;
    int* count = (int*)p;              p += rup16((size_t)N * 4);
    int* offsets = (int*)p;            p += rup16((size_t)(N + 4) * 4);
    int* cursor = (int*)p;             p += rup16((size_t)N * 4);
    int* csr_src = (int*)p;            p += rup16((size_t)E * 4);
    float* csr_alpha = (float*)p;      p += rup16((size_t)E * 4);
    unsigned* wt = (unsigned*)p;       p += 128 * 128 * 4;           // 64 KB bf16 Wt[128][256]
    unsigned* xcvt = (unsigned*)p;     p += rup16((size_t)N * 64 * 4); // 12.8 MB bf16 x copy
    unsigned* aggb = (unsigned*)p;     // N*64 u32 = 12.8 MB bf16 agg

    // zero flags + count (contiguous at start of ws)
    hipMemsetAsync(d_ws, 0, 16 + (size_t)N * 4, stream);

    int eb = (E + 255) / 256;
    int nb = (N + 3) / 4;
    int nb64 = (N + 63) / 64;
    int ncv = (N * 32 + 255) / 256;

    probe_kernel<<<1, 64, 0, stream>>>((const unsigned*)d_in[0], ei, flags);
    cvt_x<<<ncv, 256, 0, stream>>>((const float4*)d_in[0], (uint2*)xcvt, flags, N * 32);
    transpose_w<<<64, 256, 0, stream>>>((const unsigned*)d_in[3], (const float*)d_in[3],
                                        (const unsigned*)d_in[5], (const float*)d_in[5],
                                        wt, flags);
    edge_count<<<eb, 256, 0, stream>>>(ei, count, flags, E);
    scan_kernel<<<1, 1024, 0, stream>>>(count, offsets, cursor, N);
    edge_scatter<<<eb, 256, 0, stream>>>(ei, (const float*)d_in[2], (const __hip_bfloat16*)d_in[2],
                                         cursor, csr_src, csr_alpha, flags, E);
    aggregate<<<nb, 256, 0, stream>>>((const unsigned*)d_in[0], xcvt,
                                      offsets, csr_src, csr_alpha, aggb, flags, N);
    fused_mfma<<<nb64, 256, 0, stream>>>((const unsigned*)d_in[0], xcvt, aggb, (const uint4*)wt,
                                         (const float*)d_in[4], (const __hip_bfloat16*)d_in[4],
                                         (const float*)d_in[6], (const __hip_bfloat16*)d_in[6],
                                         (const float*)d_in[7], (const __hip_bfloat16*)d_in[7],
                                         (const float*)d_in[8], (const __hip_bfloat16*)d_in[8],
                                         (float*)d_out, (unsigned*)d_out, flags, N);
}

// Round 3
// 254.372 us; speedup vs baseline: 2.5864x; 1.1224x over previous
//
#include <hip/hip_runtime.h>
#include <hip/hip_bf16.h>

#define EPS 1e-9f
#define LN_EPS 1e-5f

typedef __attribute__((ext_vector_type(8))) short bf16x8;
typedef __attribute__((ext_vector_type(4))) float f32x4;

// ---------- helpers ----------
__device__ __forceinline__ float lo16(unsigned p) { return __uint_as_float(p << 16); }
__device__ __forceinline__ float hi16(unsigned p) { return __uint_as_float(p & 0xffff0000u); }
__device__ __forceinline__ unsigned f2b(float f) {
    unsigned u = __float_as_uint(f);
    return (u + 0x7fffu + ((u >> 16) & 1u)) >> 16;  // round-to-nearest-even
}
__device__ __forceinline__ int eidx(const int* ei, int i, int i64) {
    return i64 ? ei[2 * i] : ei[i];   // little-endian: low dword of int64
}
__device__ __forceinline__ float ldw(const float* fp, const __hip_bfloat16* hp, int i, int f32) {
    return f32 ? fp[i] : __bfloat162float(hp[i]);
}

// ---------- K0: dtype probe (1 wave). flags[0]=1 if floats are fp32; flags[1]=1 if idx int64 ----------
__global__ void probe_kernel(const unsigned* __restrict__ xb, const int* __restrict__ ei,
                             int* __restrict__ flags) {
    int lane = threadIdx.x & 63;
    unsigned d = xb[lane * 97];
    unsigned ex = (d >> 7) & 0xFFu;              // bf16-packed: low-half bf16 exponent field
    unsigned long long m1 = __ballot(ex >= 110u && ex <= 135u);
    int hi = ei[2 * lane + 1];                   // int64: odd dwords are all zero
    unsigned long long m2 = __ballot(hi == 0);
    if (lane == 0) {
        flags[0] = (__popcll(m1) > 32) ? 0 : 1;  // many bf16-exponent hits -> packed bf16
        flags[1] = (__popcll(m2) > 32) ? 1 : 0;
    }
}

// ---------- K1a: convert fp32 x -> packed bf16 copy (no-op in bf16 mode) ----------
__global__ void cvt_x(const float4* __restrict__ xf4, uint2* __restrict__ xcvt2,
                      const int* __restrict__ flags, int n4) {
    if (!flags[0]) return;
    int i = blockIdx.x * 256 + threadIdx.x;
    if (i >= n4) return;
    float4 v = xf4[i];
    xcvt2[i] = make_uint2(f2b(v.x) | (f2b(v.y) << 16), f2b(v.z) | (f2b(v.w) << 16));
}

// ---------- K1b: build Wt[f][k] bf16, k = 0..255 (Ws rows then Wn rows), row-major [128][256] ----------
__global__ void transpose_w(const unsigned* __restrict__ Wsb, const float* __restrict__ Wsf,
                            const unsigned* __restrict__ Wnb, const float* __restrict__ Wnf,
                            unsigned* __restrict__ wt, const int* __restrict__ flags) {
    int tid = blockIdx.x * 256 + threadIdx.x;    // 16384 threads: f = tid>>7, k-pair = tid&127
    int f = tid >> 7, k2 = tid & 127;
    int k2l = k2 & 63;
    unsigned out;
    if (flags[0]) {
        const float* W = (k2 < 64) ? Wsf : Wnf;
        float lo = W[(2 * k2l) * 128 + f], hi = W[(2 * k2l + 1) * 128 + f];
        out = f2b(lo) | (f2b(hi) << 16);
    } else {
        const unsigned* W = (k2 < 64) ? Wsb : Wnb;
        unsigned lo = W[(2 * k2l) * 64 + (f >> 1)];
        unsigned hi = W[(2 * k2l + 1) * 64 + (f >> 1)];
        unsigned a = (f & 1) ? (lo >> 16) : (lo & 0xffffu);
        unsigned b = (f & 1) ? (hi & 0xffff0000u) : (hi << 16);
        out = a | b;
    }
    wt[tid] = out;
}

// ---------- K2: per-target degree count + compact int32 tgt array ----------
__global__ void edge_count(const int* __restrict__ ei, int* __restrict__ count,
                           int* __restrict__ tgt32, const int* __restrict__ flags, int E) {
    int e = blockIdx.x * 256 + threadIdx.x;
    if (e >= E) return;
    int t = eidx(ei, E + e, flags[1]);
    tgt32[e] = t;
    atomicAdd(&count[t], 1);
}

// ---------- K3: single-block exclusive scan, 4 elems/thread (13 iters for N=50k) ----------
__global__ void scan_kernel(const int* __restrict__ count, int* __restrict__ offsets,
                            int* __restrict__ cursor, int N) {
    __shared__ int wsum[16];
    __shared__ int s_carry;
    int tid = threadIdx.x, lane = tid & 63, w = tid >> 6;
    if (tid == 0) s_carry = 0;
    __syncthreads();
    for (int base = 0; base < N; base += 4096) {
        int i0 = base + tid * 4;
        int4 v;
        if (i0 + 3 < N) v = *(const int4*)(count + i0);
        else {
            v.x = (i0     < N) ? count[i0]     : 0;
            v.y = (i0 + 1 < N) ? count[i0 + 1] : 0;
            v.z = (i0 + 2 < N) ? count[i0 + 2] : 0;
            v.w = (i0 + 3 < N) ? count[i0 + 3] : 0;
        }
        int s = v.x + v.y + v.z + v.w;
        int incl = s;
        #pragma unroll
        for (int off = 1; off < 64; off <<= 1) {
            int t = __shfl_up(incl, off);
            if (lane >= off) incl += t;
        }
        if (lane == 63) wsum[w] = incl;
        __syncthreads();
        int wpre = 0, tot = 0;
        #pragma unroll
        for (int j = 0; j < 16; ++j) { int sj = wsum[j]; if (j < w) wpre += sj; tot += sj; }
        int o0 = s_carry + wpre + incl - s;
        int o1 = o0 + v.x, o2 = o1 + v.y, o3 = o2 + v.z;
        if (i0 + 3 < N) {
            *(int4*)(offsets + i0) = make_int4(o0, o1, o2, o3);
            *(int4*)(cursor + i0)  = make_int4(o0, o1, o2, o3);
        } else {
            if (i0     < N) { offsets[i0]     = o0; cursor[i0]     = o0; }
            if (i0 + 1 < N) { offsets[i0 + 1] = o1; cursor[i0 + 1] = o1; }
            if (i0 + 2 < N) { offsets[i0 + 2] = o2; cursor[i0 + 2] = o2; }
        }
        __syncthreads();
        if (tid == 0) s_carry += tot;
        __syncthreads();
    }
    if (threadIdx.x == 0) offsets[N] = s_carry;
}

// ---------- K4: scatter edges into CSR buckets; payload = {src, exp(w)} in one 8B store ----------
__global__ void edge_scatter(const int* __restrict__ ei, const int* __restrict__ tgt32,
                             const float* __restrict__ ewf, const __hip_bfloat16* __restrict__ ewh,
                             int* __restrict__ cursor, uint2* __restrict__ csr,
                             const int* __restrict__ flags, int E) {
    int e = blockIdx.x * 256 + threadIdx.x;
    if (e >= E) return;
    int f32 = flags[0], i64 = flags[1];
    int t = tgt32[e];
    int s = eidx(ei, e, i64);
    float w = ldw(ewf, ewh, e, f32);
    float al = expf(w);                          // unnormalized: softmax denom cancels in proj-norm
    int pos = atomicAdd(&cursor[t], 1);
    csr[pos] = make_uint2((unsigned)s, __float_as_uint(al));
}

// ---------- K5: one wave per target node; 8-deep pipelined gather of bf16 x[src] rows ----------
__global__ void aggregate(const unsigned* __restrict__ xb, const unsigned* __restrict__ xcvt,
                          const int* __restrict__ offsets, const uint2* __restrict__ csr,
                          unsigned* __restrict__ aggb, const int* __restrict__ flags, int N) {
    int node = blockIdx.x * 4 + (threadIdx.x >> 6);
    if (node >= N) return;
    int lane = threadIdx.x & 63;
    const unsigned* xs = flags[0] ? xcvt : xb;   // always gather bf16 (half traffic)
    float a0 = 0.f, a1 = 0.f;
    int beg = offsets[node], end = offsets[node + 1];
    int j = beg;
    for (; j + 8 <= end; j += 8) {               // 8 independent gathers in flight
        uint2 e0 = csr[j+0], e1 = csr[j+1], e2 = csr[j+2], e3 = csr[j+3],
              e4 = csr[j+4], e5 = csr[j+5], e6 = csr[j+6], e7 = csr[j+7];
        unsigned p0 = xs[e0.x * 64 + lane], p1 = xs[e1.x * 64 + lane],
                 p2 = xs[e2.x * 64 + lane], p3 = xs[e3.x * 64 + lane],
                 p4 = xs[e4.x * 64 + lane], p5 = xs[e5.x * 64 + lane],
                 p6 = xs[e6.x * 64 + lane], p7 = xs[e7.x * 64 + lane];
        float l0 = __uint_as_float(e0.y), l1 = __uint_as_float(e1.y),
              l2 = __uint_as_float(e2.y), l3 = __uint_as_float(e3.y),
              l4 = __uint_as_float(e4.y), l5 = __uint_as_float(e5.y),
              l6 = __uint_as_float(e6.y), l7 = __uint_as_float(e7.y);
        a0 += l0 * lo16(p0); a1 += l0 * hi16(p0);
        a0 += l1 * lo16(p1); a1 += l1 * hi16(p1);
        a0 += l2 * lo16(p2); a1 += l2 * hi16(p2);
        a0 += l3 * lo16(p3); a1 += l3 * hi16(p3);
        a0 += l4 * lo16(p4); a1 += l4 * hi16(p4);
        a0 += l5 * lo16(p5); a1 += l5 * hi16(p5);
        a0 += l6 * lo16(p6); a1 += l6 * hi16(p6);
        a0 += l7 * lo16(p7); a1 += l7 * hi16(p7);
    }
    for (; j + 4 <= end; j += 4) {
        uint2 e0 = csr[j+0], e1 = csr[j+1], e2 = csr[j+2], e3 = csr[j+3];
        unsigned p0 = xs[e0.x * 64 + lane], p1 = xs[e1.x * 64 + lane],
                 p2 = xs[e2.x * 64 + lane], p3 = xs[e3.x * 64 + lane];
        float l0 = __uint_as_float(e0.y), l1 = __uint_as_float(e1.y),
              l2 = __uint_as_float(e2.y), l3 = __uint_as_float(e3.y);
        a0 += l0 * lo16(p0); a1 += l0 * hi16(p0);
        a0 += l1 * lo16(p1); a1 += l1 * hi16(p1);
        a0 += l2 * lo16(p2); a1 += l2 * hi16(p2);
        a0 += l3 * lo16(p3); a1 += l3 * hi16(p3);
    }
    for (; j < end; ++j) {
        uint2 e = csr[j];
        unsigned p = xs[e.x * 64 + lane];
        float l = __uint_as_float(e.y);
        a0 += l * lo16(p); a1 += l * hi16(p);
    }
    float ss = a0 * a0 + a1 * a1;
    #pragma unroll
    for (int m = 32; m >= 1; m >>= 1) ss += __shfl_xor(ss, m);
    float inv = 1.f / (sqrtf(ss) + EPS);
    aggb[node * 64 + lane] = f2b(a0 * inv) | (f2b(a1 * inv) << 16);
}

// ---------- K6: MFMA fused: C = 0.5*([x|agg] @ [Ws;Wn] + bs + bn) -> proj-norm -> LN ----------
// 64 nodes/block, 4 waves x 16 nodes. A = [x|agg] bf16 staged in XOR-swizzled LDS.
// B = Wt[f][k] bf16 from global (L1/L2 resident, 64 KB total).
// mfma_f32_16x16x32_bf16: C/D: col = lane&15, row = (lane>>4)*4 + reg  [learn_hip m89].
__global__ __launch_bounds__(256) void fused_mfma(
    const unsigned* __restrict__ xb, const unsigned* __restrict__ xcvt,
    const unsigned* __restrict__ aggb, const uint4* __restrict__ wt4,
    const float* __restrict__ bsf, const __hip_bfloat16* __restrict__ bsh,
    const float* __restrict__ bnf, const __hip_bfloat16* __restrict__ bnh,
    const float* __restrict__ gf, const __hip_bfloat16* __restrict__ gh,
    const float* __restrict__ tf, const __hip_bfloat16* __restrict__ th,
    float* __restrict__ outf, unsigned* __restrict__ outb,
    const int* __restrict__ flags, int N)
{
    __shared__ uint4 sA[2048];                   // 64 rows x 32 chunks of 16B = 32 KB
    int f32 = flags[0];
    const uint4* xs4 = (const uint4*)(f32 ? xcvt : xb);
    const uint4* ag4 = (const uint4*)aggb;
    int tid = threadIdx.x;
    int node0 = blockIdx.x * 64;

    // stage A: row r = [x bf16 (chunks 0-15) | agg bf16 (chunks 16-31)], XOR-swizzled
    #pragma unroll
    for (int i = 0; i < 8; ++i) {
        int ci = i * 256 + tid;
        int r = ci >> 5, c = ci & 31;
        int node = node0 + r;
        uint4 v = make_uint4(0, 0, 0, 0);
        if (node < N) v = (c < 16) ? xs4[node * 16 + c] : ag4[node * 16 + (c - 16)];
        sA[r * 32 + (c ^ (r & 15))] = v;
    }
    __syncthreads();

    int lane = tid & 63, w = tid >> 6, g = lane >> 4, c16 = lane & 15;
    int rloc = w * 16 + c16;                     // A row this lane reads

    f32x4 acc[8];
    #pragma unroll
    for (int t = 0; t < 8; ++t) acc[t] = (f32x4){0.f, 0.f, 0.f, 0.f};

    #pragma unroll
    for (int kk = 0; kk < 8; ++kk) {             // K = 256 in steps of 32
        uint4 av = sA[rloc * 32 + ((kk * 4 + g) ^ c16)];
        bf16x8 a = __builtin_bit_cast(bf16x8, av);
        #pragma unroll
        for (int t = 0; t < 8; ++t) {            // 8 feature tiles of 16
            uint4 bv = wt4[(t * 16 + c16) * 32 + kk * 4 + g];
            bf16x8 b = __builtin_bit_cast(bf16x8, bv);
            acc[t] = __builtin_amdgcn_mfma_f32_16x16x32_bf16(a, b, acc[t], 0, 0, 0);
        }
    }

    // per-lane feature params (features f = t*16 + c16)
    float bsum[8], gam[8], bet[8];
    #pragma unroll
    for (int t = 0; t < 8; ++t) {
        int f = t * 16 + c16;
        bsum[t] = ldw(bsf, bsh, f, f32) + ldw(bnf, bnh, f, f32);
        gam[t]  = ldw(gf, gh, f, f32);
        bet[t]  = ldw(tf, th, f, f32);
    }

    // epilogue: per node (4 per lane, one per acc reg), reduce over 16-lane group
    #pragma unroll
    for (int reg = 0; reg < 4; ++reg) {
        int node = node0 + w * 16 + g * 4 + reg;
        float cv[8], s1 = 0.f, s2 = 0.f;
        #pragma unroll
        for (int t = 0; t < 8; ++t) {
            float c_ = 0.5f * (acc[t][reg] + bsum[t]);
            cv[t] = c_; s1 += c_; s2 += c_ * c_;
        }
        #pragma unroll
        for (int m = 1; m < 16; m <<= 1) { s1 += __shfl_xor(s1, m); s2 += __shfl_xor(s2, m); }
        float inv  = 1.f / (sqrtf(s2) + EPS);
        float mean = s1 * inv * (1.f / 128.f);
        float var  = s2 * inv * inv * (1.f / 128.f) - mean * mean;
        float rstd = 1.f / sqrtf(var + LN_EPS);
        if (f32) {
            if (node < N) {
                #pragma unroll
                for (int t = 0; t < 8; ++t) {
                    float o = (cv[t] * inv - mean) * rstd * gam[t] + bet[t];
                    outf[(size_t)node * 128 + t * 16 + c16] = o;
                }
            }
        } else {
            #pragma unroll
            for (int t = 0; t < 8; ++t) {
                float o = (cv[t] * inv - mean) * rstd * gam[t] + bet[t];
                float po = __shfl_xor(o, 1);
                if (!(c16 & 1) && node < N)
                    outb[node * 64 + t * 8 + (c16 >> 1)] = f2b(o) | (f2b(po) << 16);
            }
        }
    }
}

static inline size_t rup16(size_t x) { return (x + 15) & ~(size_t)15; }

extern "C" void kernel_launch(void* const* d_in, const int* in_sizes, int n_in,
                              void* d_out, int out_size, void* d_ws, size_t ws_size,
                              hipStream_t stream) {
    int N = in_sizes[0] / 128;
    int E = in_sizes[1] / 2;
    const int* ei = (const int*)d_in[1];

    char* p = (char*)d_ws;
    int* flags = (int*)p;              p += 16;
    int* count = (int*)p;              p += rup16((size_t)N * 4);
    int* offsets = (int*)p;            p += rup16((size_t)(N + 4) * 4);
    int* cursor = (int*)p;             p += rup16((size_t)N * 4);
    int* tgt32 = (int*)p;              p += rup16((size_t)E * 4);
    uint2* csr = (uint2*)p;            p += rup16((size_t)E * 8);
    unsigned* wt = (unsigned*)p;       p += 128 * 128 * 4;             // 64 KB bf16 Wt[128][256]
    unsigned* xcvt = (unsigned*)p;     p += rup16((size_t)N * 64 * 4); // 12.8 MB bf16 x copy
    unsigned* aggb = (unsigned*)p;     // N*64 u32 = 12.8 MB bf16 agg

    // zero flags + count (contiguous at start of ws)
    hipMemsetAsync(d_ws, 0, 16 + (size_t)N * 4, stream);

    int eb = (E + 255) / 256;
    int nb = (N + 3) / 4;
    int nb64 = (N + 63) / 64;
    int ncv = (N * 32 + 255) / 256;

    probe_kernel<<<1, 64, 0, stream>>>((const unsigned*)d_in[0], ei, flags);
    cvt_x<<<ncv, 256, 0, stream>>>((const float4*)d_in[0], (uint2*)xcvt, flags, N * 32);
    transpose_w<<<64, 256, 0, stream>>>((const unsigned*)d_in[3], (const float*)d_in[3],
                                        (const unsigned*)d_in[5], (const float*)d_in[5],
                                        wt, flags);
    edge_count<<<eb, 256, 0, stream>>>(ei, count, tgt32, flags, E);
    scan_kernel<<<1, 1024, 0, stream>>>(count, offsets, cursor, N);
    edge_scatter<<<eb, 256, 0, stream>>>(ei, tgt32, (const float*)d_in[2],
                                         (const __hip_bfloat16*)d_in[2],
                                         cursor, csr, flags, E);
    aggregate<<<nb, 256, 0, stream>>>((const unsigned*)d_in[0], xcvt,
                                      offsets, csr, aggb, flags, N);
    fused_mfma<<<nb64, 256, 0, stream>>>((const unsigned*)d_in[0], xcvt, aggb, (const uint4*)wt,
                                         (const float*)d_in[4], (const __hip_bfloat16*)d_in[4],
                                         (const float*)d_in[6], (const __hip_bfloat16*)d_in[6],
                                         (const float*)d_in[7], (const __hip_bfloat16*)d_in[7],
                                         (const float*)d_in[8], (const __hip_bfloat16*)d_in[8],
                                         (float*)d_out, (unsigned*)d_out, flags, N);
}

// Round 4
// 226.620 us; speedup vs baseline: 2.9031x; 1.1225x over previous
//
#include <hip/hip_runtime.h>
#include <hip/hip_bf16.h>

#define EPS 1e-9f
#define LN_EPS 1e-5f

typedef __attribute__((ext_vector_type(8))) short bf16x8;
typedef __attribute__((ext_vector_type(4))) float f32x4;

// ---------- helpers ----------
__device__ __forceinline__ float lo16(unsigned p) { return __uint_as_float(p << 16); }
__device__ __forceinline__ float hi16(unsigned p) { return __uint_as_float(p & 0xffff0000u); }
__device__ __forceinline__ unsigned f2b(float f) {
    unsigned u = __float_as_uint(f);
    return (u + 0x7fffu + ((u >> 16) & 1u)) >> 16;  // round-to-nearest-even
}
__device__ __forceinline__ int eidx(const int* ei, int i, int i64) {
    return i64 ? ei[2 * i] : ei[i];   // little-endian: low dword of int64
}
__device__ __forceinline__ float ldw(const float* fp, const __hip_bfloat16* hp, int i, int f32) {
    return f32 ? fp[i] : __bfloat162float(hp[i]);
}

// ---------- K0: dtype probe (1 wave). flags[0]=1 if floats are fp32; flags[1]=1 if idx int64 ----------
__global__ void probe_kernel(const unsigned* __restrict__ xb, const int* __restrict__ ei,
                             int* __restrict__ flags) {
    int lane = threadIdx.x & 63;
    unsigned d = xb[lane * 97];
    unsigned ex = (d >> 7) & 0xFFu;              // bf16-packed: low-half bf16 exponent field
    unsigned long long m1 = __ballot(ex >= 110u && ex <= 135u);
    int hi = ei[2 * lane + 1];                   // int64: odd dwords are all zero
    unsigned long long m2 = __ballot(hi == 0);
    if (lane == 0) {
        flags[0] = (__popcll(m1) > 32) ? 0 : 1;  // many bf16-exponent hits -> packed bf16
        flags[1] = (__popcll(m2) > 32) ? 1 : 0;
    }
}

// ---------- K1a: convert fp32 x -> packed bf16 copy (no-op in bf16 mode) ----------
__global__ void cvt_x(const float4* __restrict__ xf4, uint2* __restrict__ xcvt2,
                      const int* __restrict__ flags, int n4) {
    if (!flags[0]) return;
    int i = blockIdx.x * 256 + threadIdx.x;
    if (i >= n4) return;
    float4 v = xf4[i];
    xcvt2[i] = make_uint2(f2b(v.x) | (f2b(v.y) << 16), f2b(v.z) | (f2b(v.w) << 16));
}

// ---------- K1b: build Wt[f][k] bf16, k = 0..255 (Ws rows then Wn rows), row-major [128][256] ----------
__global__ void transpose_w(const unsigned* __restrict__ Wsb, const float* __restrict__ Wsf,
                            const unsigned* __restrict__ Wnb, const float* __restrict__ Wnf,
                            unsigned* __restrict__ wt, const int* __restrict__ flags) {
    int tid = blockIdx.x * 256 + threadIdx.x;    // 16384 threads: f = tid>>7, k-pair = tid&127
    int f = tid >> 7, k2 = tid & 127;
    int k2l = k2 & 63;
    unsigned out;
    if (flags[0]) {
        const float* W = (k2 < 64) ? Wsf : Wnf;
        float lo = W[(2 * k2l) * 128 + f], hi = W[(2 * k2l + 1) * 128 + f];
        out = f2b(lo) | (f2b(hi) << 16);
    } else {
        const unsigned* W = (k2 < 64) ? Wsb : Wnb;
        unsigned lo = W[(2 * k2l) * 64 + (f >> 1)];
        unsigned hi = W[(2 * k2l + 1) * 64 + (f >> 1)];
        unsigned a = (f & 1) ? (lo >> 16) : (lo & 0xffffu);
        unsigned b = (f & 1) ? (hi & 0xffff0000u) : (hi << 16);
        out = a | b;
    }
    wt[tid] = out;
}

// ---------- K2: per-target degree count + arrival rank + compact int32 tgt (4 edges/thread) ----------
__global__ void edge_count(const int* __restrict__ ei, int* __restrict__ count,
                           int* __restrict__ tgt32, int* __restrict__ rank,
                           const int* __restrict__ flags, int E) {
    int e0 = (blockIdx.x * 256 + threadIdx.x) * 4;
    if (e0 >= E) return;
    int i64 = flags[1];
    if (e0 + 4 <= E) {
        int t0 = eidx(ei, E + e0 + 0, i64), t1 = eidx(ei, E + e0 + 1, i64),
            t2 = eidx(ei, E + e0 + 2, i64), t3 = eidx(ei, E + e0 + 3, i64);
        int r0 = atomicAdd(&count[t0], 1), r1 = atomicAdd(&count[t1], 1),
            r2 = atomicAdd(&count[t2], 1), r3 = atomicAdd(&count[t3], 1);
        *(int4*)(tgt32 + e0) = make_int4(t0, t1, t2, t3);
        *(int4*)(rank + e0)  = make_int4(r0, r1, r2, r3);
    } else {
        for (int j = 0; j < 4 && e0 + j < E; ++j) {
            int t = eidx(ei, E + e0 + j, i64);
            rank[e0 + j] = atomicAdd(&count[t], 1);
            tgt32[e0 + j] = t;
        }
    }
}

// ---------- K3: single-block exclusive scan, 4 elems/thread (13 iters for N=50k) ----------
__global__ void scan_kernel(const int* __restrict__ count, int* __restrict__ offsets, int N) {
    __shared__ int wsum[16];
    __shared__ int s_carry;
    int tid = threadIdx.x, lane = tid & 63, w = tid >> 6;
    if (tid == 0) s_carry = 0;
    __syncthreads();
    for (int base = 0; base < N; base += 4096) {
        int i0 = base + tid * 4;
        int4 v;
        if (i0 + 3 < N) v = *(const int4*)(count + i0);
        else {
            v.x = (i0     < N) ? count[i0]     : 0;
            v.y = (i0 + 1 < N) ? count[i0 + 1] : 0;
            v.z = (i0 + 2 < N) ? count[i0 + 2] : 0;
            v.w = (i0 + 3 < N) ? count[i0 + 3] : 0;
        }
        int s = v.x + v.y + v.z + v.w;
        int incl = s;
        #pragma unroll
        for (int off = 1; off < 64; off <<= 1) {
            int t = __shfl_up(incl, off);
            if (lane >= off) incl += t;
        }
        if (lane == 63) wsum[w] = incl;
        __syncthreads();
        int wpre = 0, tot = 0;
        #pragma unroll
        for (int j = 0; j < 16; ++j) { int sj = wsum[j]; if (j < w) wpre += sj; tot += sj; }
        int o0 = s_carry + wpre + incl - s;
        int o1 = o0 + v.x, o2 = o1 + v.y, o3 = o2 + v.z;
        if (i0 + 3 < N) {
            *(int4*)(offsets + i0) = make_int4(o0, o1, o2, o3);
        } else {
            if (i0     < N) offsets[i0]     = o0;
            if (i0 + 1 < N) offsets[i0 + 1] = o1;
            if (i0 + 2 < N) offsets[i0 + 2] = o2;
        }
        __syncthreads();
        if (tid == 0) s_carry += tot;
        __syncthreads();
    }
    if (threadIdx.x == 0) offsets[N] = s_carry;
}

// ---------- K4: atomic-free scatter: pos = offsets[t] + rank[e] (4 edges/thread) ----------
__global__ void edge_scatter(const int* __restrict__ ei, const int* __restrict__ tgt32,
                             const int* __restrict__ rank,
                             const float* __restrict__ ewf, const __hip_bfloat16* __restrict__ ewh,
                             const int* __restrict__ offsets, uint2* __restrict__ csr,
                             const int* __restrict__ flags, int E) {
    int e0 = (blockIdx.x * 256 + threadIdx.x) * 4;
    if (e0 >= E) return;
    int f32 = flags[0], i64 = flags[1];
    if (e0 + 4 <= E) {
        int4 t = *(const int4*)(tgt32 + e0);
        int4 r = *(const int4*)(rank + e0);
        int s0 = eidx(ei, e0 + 0, i64), s1 = eidx(ei, e0 + 1, i64),
            s2 = eidx(ei, e0 + 2, i64), s3 = eidx(ei, e0 + 3, i64);
        float w0 = ldw(ewf, ewh, e0 + 0, f32), w1 = ldw(ewf, ewh, e0 + 1, f32),
              w2 = ldw(ewf, ewh, e0 + 2, f32), w3 = ldw(ewf, ewh, e0 + 3, f32);
        int o0 = offsets[t.x], o1 = offsets[t.y], o2 = offsets[t.z], o3 = offsets[t.w];
        csr[o0 + r.x] = make_uint2((unsigned)s0, __float_as_uint(expf(w0)));
        csr[o1 + r.y] = make_uint2((unsigned)s1, __float_as_uint(expf(w1)));
        csr[o2 + r.z] = make_uint2((unsigned)s2, __float_as_uint(expf(w2)));
        csr[o3 + r.w] = make_uint2((unsigned)s3, __float_as_uint(expf(w3)));
    } else {
        for (int j = 0; j < 4 && e0 + j < E; ++j) {
            int e = e0 + j;
            int t = tgt32[e];
            int s = eidx(ei, e, i64);
            float w = ldw(ewf, ewh, e, f32);
            csr[offsets[t] + rank[e]] = make_uint2((unsigned)s, __float_as_uint(expf(w)));
        }
    }
}

// ---------- K5: one wave per target node; 8-deep pipelined gather of bf16 x[src] rows ----------
__global__ void aggregate(const unsigned* __restrict__ xb, const unsigned* __restrict__ xcvt,
                          const int* __restrict__ offsets, const uint2* __restrict__ csr,
                          unsigned* __restrict__ aggb, const int* __restrict__ flags, int N) {
    int node = blockIdx.x * 4 + (threadIdx.x >> 6);
    if (node >= N) return;
    int lane = threadIdx.x & 63;
    const unsigned* xs = flags[0] ? xcvt : xb;   // always gather bf16 (half traffic)
    float a0 = 0.f, a1 = 0.f;
    int beg = offsets[node], end = offsets[node + 1];
    int j = beg;
    for (; j + 8 <= end; j += 8) {               // 8 independent gathers in flight
        uint2 e0 = csr[j+0], e1 = csr[j+1], e2 = csr[j+2], e3 = csr[j+3],
              e4 = csr[j+4], e5 = csr[j+5], e6 = csr[j+6], e7 = csr[j+7];
        unsigned p0 = xs[e0.x * 64 + lane], p1 = xs[e1.x * 64 + lane],
                 p2 = xs[e2.x * 64 + lane], p3 = xs[e3.x * 64 + lane],
                 p4 = xs[e4.x * 64 + lane], p5 = xs[e5.x * 64 + lane],
                 p6 = xs[e6.x * 64 + lane], p7 = xs[e7.x * 64 + lane];
        float l0 = __uint_as_float(e0.y), l1 = __uint_as_float(e1.y),
              l2 = __uint_as_float(e2.y), l3 = __uint_as_float(e3.y),
              l4 = __uint_as_float(e4.y), l5 = __uint_as_float(e5.y),
              l6 = __uint_as_float(e6.y), l7 = __uint_as_float(e7.y);
        a0 += l0 * lo16(p0); a1 += l0 * hi16(p0);
        a0 += l1 * lo16(p1); a1 += l1 * hi16(p1);
        a0 += l2 * lo16(p2); a1 += l2 * hi16(p2);
        a0 += l3 * lo16(p3); a1 += l3 * hi16(p3);
        a0 += l4 * lo16(p4); a1 += l4 * hi16(p4);
        a0 += l5 * lo16(p5); a1 += l5 * hi16(p5);
        a0 += l6 * lo16(p6); a1 += l6 * hi16(p6);
        a0 += l7 * lo16(p7); a1 += l7 * hi16(p7);
    }
    for (; j + 4 <= end; j += 4) {
        uint2 e0 = csr[j+0], e1 = csr[j+1], e2 = csr[j+2], e3 = csr[j+3];
        unsigned p0 = xs[e0.x * 64 + lane], p1 = xs[e1.x * 64 + lane],
                 p2 = xs[e2.x * 64 + lane], p3 = xs[e3.x * 64 + lane];
        float l0 = __uint_as_float(e0.y), l1 = __uint_as_float(e1.y),
              l2 = __uint_as_float(e2.y), l3 = __uint_as_float(e3.y);
        a0 += l0 * lo16(p0); a1 += l0 * hi16(p0);
        a0 += l1 * lo16(p1); a1 += l1 * hi16(p1);
        a0 += l2 * lo16(p2); a1 += l2 * hi16(p2);
        a0 += l3 * lo16(p3); a1 += l3 * hi16(p3);
    }
    for (; j < end; ++j) {
        uint2 e = csr[j];
        unsigned p = xs[e.x * 64 + lane];
        float l = __uint_as_float(e.y);
        a0 += l * lo16(p); a1 += l * hi16(p);
    }
    float ss = a0 * a0 + a1 * a1;
    #pragma unroll
    for (int m = 32; m >= 1; m >>= 1) ss += __shfl_xor(ss, m);
    float inv = 1.f / (sqrtf(ss) + EPS);
    aggb[node * 64 + lane] = f2b(a0 * inv) | (f2b(a1 * inv) << 16);
}

// ---------- K6: MFMA fused: C = 0.5*([x|agg] @ [Ws;Wn] + bs + bn) -> proj-norm -> LN ----------
// 64 nodes/block, 4 waves x 16 nodes. A = [x|agg] bf16 staged in XOR-swizzled LDS.
// B = Wt[f][k] bf16 from global (L1/L2 resident, 64 KB total).
// mfma_f32_16x16x32_bf16: C/D: col = lane&15, row = (lane>>4)*4 + reg  [learn_hip m89].
__global__ __launch_bounds__(256) void fused_mfma(
    const unsigned* __restrict__ xb, const unsigned* __restrict__ xcvt,
    const unsigned* __restrict__ aggb, const uint4* __restrict__ wt4,
    const float* __restrict__ bsf, const __hip_bfloat16* __restrict__ bsh,
    const float* __restrict__ bnf, const __hip_bfloat16* __restrict__ bnh,
    const float* __restrict__ gf, const __hip_bfloat16* __restrict__ gh,
    const float* __restrict__ tf, const __hip_bfloat16* __restrict__ th,
    float* __restrict__ outf, unsigned* __restrict__ outb,
    const int* __restrict__ flags, int N)
{
    __shared__ uint4 sA[2048];                   // 64 rows x 32 chunks of 16B = 32 KB
    int f32 = flags[0];
    const uint4* xs4 = (const uint4*)(f32 ? xcvt : xb);
    const uint4* ag4 = (const uint4*)aggb;
    int tid = threadIdx.x;
    int node0 = blockIdx.x * 64;

    // stage A: row r = [x bf16 (chunks 0-15) | agg bf16 (chunks 16-31)], XOR-swizzled
    #pragma unroll
    for (int i = 0; i < 8; ++i) {
        int ci = i * 256 + tid;
        int r = ci >> 5, c = ci & 31;
        int node = node0 + r;
        uint4 v = make_uint4(0, 0, 0, 0);
        if (node < N) v = (c < 16) ? xs4[node * 16 + c] : ag4[node * 16 + (c - 16)];
        sA[r * 32 + (c ^ (r & 15))] = v;
    }
    __syncthreads();

    int lane = tid & 63, w = tid >> 6, g = lane >> 4, c16 = lane & 15;
    int rloc = w * 16 + c16;                     // A row this lane reads

    f32x4 acc[8];
    #pragma unroll
    for (int t = 0; t < 8; ++t) acc[t] = (f32x4){0.f, 0.f, 0.f, 0.f};

    #pragma unroll
    for (int kk = 0; kk < 8; ++kk) {             // K = 256 in steps of 32
        uint4 av = sA[rloc * 32 + ((kk * 4 + g) ^ c16)];
        bf16x8 a = __builtin_bit_cast(bf16x8, av);
        #pragma unroll
        for (int t = 0; t < 8; ++t) {            // 8 feature tiles of 16
            uint4 bv = wt4[(t * 16 + c16) * 32 + kk * 4 + g];
            bf16x8 b = __builtin_bit_cast(bf16x8, bv);
            acc[t] = __builtin_amdgcn_mfma_f32_16x16x32_bf16(a, b, acc[t], 0, 0, 0);
        }
    }

    // per-lane feature params (features f = t*16 + c16)
    float bsum[8], gam[8], bet[8];
    #pragma unroll
    for (int t = 0; t < 8; ++t) {
        int f = t * 16 + c16;
        bsum[t] = ldw(bsf, bsh, f, f32) + ldw(bnf, bnh, f, f32);
        gam[t]  = ldw(gf, gh, f, f32);
        bet[t]  = ldw(tf, th, f, f32);
    }

    // epilogue: per node (4 per lane, one per acc reg), reduce over 16-lane group
    #pragma unroll
    for (int reg = 0; reg < 4; ++reg) {
        int node = node0 + w * 16 + g * 4 + reg;
        float cv[8], s1 = 0.f, s2 = 0.f;
        #pragma unroll
        for (int t = 0; t < 8; ++t) {
            float c_ = 0.5f * (acc[t][reg] + bsum[t]);
            cv[t] = c_; s1 += c_; s2 += c_ * c_;
        }
        #pragma unroll
        for (int m = 1; m < 16; m <<= 1) { s1 += __shfl_xor(s1, m); s2 += __shfl_xor(s2, m); }
        float inv  = 1.f / (sqrtf(s2) + EPS);
        float mean = s1 * inv * (1.f / 128.f);
        float var  = s2 * inv * inv * (1.f / 128.f) - mean * mean;
        float rstd = 1.f / sqrtf(var + LN_EPS);
        if (f32) {
            if (node < N) {
                #pragma unroll
                for (int t = 0; t < 8; ++t) {
                    float o = (cv[t] * inv - mean) * rstd * gam[t] + bet[t];
                    outf[(size_t)node * 128 + t * 16 + c16] = o;
                }
            }
        } else {
            #pragma unroll
            for (int t = 0; t < 8; ++t) {
                float o = (cv[t] * inv - mean) * rstd * gam[t] + bet[t];
                float po = __shfl_xor(o, 1);
                if (!(c16 & 1) && node < N)
                    outb[node * 64 + t * 8 + (c16 >> 1)] = f2b(o) | (f2b(po) << 16);
            }
        }
    }
}

static inline size_t rup16(size_t x) { return (x + 15) & ~(size_t)15; }

extern "C" void kernel_launch(void* const* d_in, const int* in_sizes, int n_in,
                              void* d_out, int out_size, void* d_ws, size_t ws_size,
                              hipStream_t stream) {
    int N = in_sizes[0] / 128;
    int E = in_sizes[1] / 2;
    const int* ei = (const int*)d_in[1];

    char* p = (char*)d_ws;
    int* flags = (int*)p;              p += 16;
    int* count = (int*)p;              p += rup16((size_t)N * 4);
    int* offsets = (int*)p;            p += rup16((size_t)(N + 4) * 4);
    int* tgt32 = (int*)p;              p += rup16((size_t)E * 4);
    int* rank = (int*)p;               p += rup16((size_t)E * 4);
    uint2* csr = (uint2*)p;            p += rup16((size_t)E * 8);
    unsigned* wt = (unsigned*)p;       p += 128 * 128 * 4;             // 64 KB bf16 Wt[128][256]
    unsigned* xcvt = (unsigned*)p;     p += rup16((size_t)N * 64 * 4); // 12.8 MB bf16 x copy
    unsigned* aggb = (unsigned*)p;     // N*64 u32 = 12.8 MB bf16 agg

    // zero flags + count (contiguous at start of ws)
    hipMemsetAsync(d_ws, 0, 16 + (size_t)N * 4, stream);

    int eb4 = (E + 1023) / 1024;
    int nb = (N + 3) / 4;
    int nb64 = (N + 63) / 64;
    int ncv = (N * 32 + 255) / 256;

    probe_kernel<<<1, 64, 0, stream>>>((const unsigned*)d_in[0], ei, flags);
    cvt_x<<<ncv, 256, 0, stream>>>((const float4*)d_in[0], (uint2*)xcvt, flags, N * 32);
    transpose_w<<<64, 256, 0, stream>>>((const unsigned*)d_in[3], (const float*)d_in[3],
                                        (const unsigned*)d_in[5], (const float*)d_in[5],
                                        wt, flags);
    edge_count<<<eb4, 256, 0, stream>>>(ei, count, tgt32, rank, flags, E);
    scan_kernel<<<1, 1024, 0, stream>>>(count, offsets, N);
    edge_scatter<<<eb4, 256, 0, stream>>>(ei, tgt32, rank, (const float*)d_in[2],
                                          (const __hip_bfloat16*)d_in[2],
                                          offsets, csr, flags, E);
    aggregate<<<nb, 256, 0, stream>>>((const unsigned*)d_in[0], xcvt,
                                      offsets, csr, aggb, flags, N);
    fused_mfma<<<nb64, 256, 0, stream>>>((const unsigned*)d_in[0], xcvt, aggb, (const uint4*)wt,
                                         (const float*)d_in[4], (const __hip_bfloat16*)d_in[4],
                                         (const float*)d_in[6], (const __hip_bfloat16*)d_in[6],
                                         (const float*)d_in[7], (const __hip_bfloat16*)d_in[7],
                                         (const float*)d_in[8], (const __hip_bfloat16*)d_in[8],
                                         (float*)d_out, (unsigned*)d_out, flags, N);
}

// Round 5
// 209.117 us; speedup vs baseline: 3.1461x; 1.0837x over previous
//
#include <hip/hip_runtime.h>
#include <hip/hip_bf16.h>
#include <hip/hip_fp16.h>

#define EPS 1e-9f
#define LN_EPS 1e-5f

typedef __attribute__((ext_vector_type(8))) short bf16x8;
typedef __attribute__((ext_vector_type(4))) float f32x4;

// ---------- helpers ----------
__device__ __forceinline__ float lo16(unsigned p) { return __uint_as_float(p << 16); }
__device__ __forceinline__ float hi16(unsigned p) { return __uint_as_float(p & 0xffff0000u); }
__device__ __forceinline__ unsigned f2b(float f) {
    unsigned u = __float_as_uint(f);
    return (u + 0x7fffu + ((u >> 16) & 1u)) >> 16;  // round-to-nearest-even
}
__device__ __forceinline__ int eidx(const int* ei, int i, int i64) {
    return i64 ? ei[2 * i] : ei[i];   // little-endian: low dword of int64
}
__device__ __forceinline__ float ldw(const float* fp, const __hip_bfloat16* hp, int i, int f32) {
    return f32 ? fp[i] : __bfloat162float(hp[i]);
}

// ---------- K0: dtype probe (1 wave). flags[0]=1 if floats are fp32; flags[1]=1 if idx int64 ----------
__global__ void probe_kernel(const unsigned* __restrict__ xb, const int* __restrict__ ei,
                             int* __restrict__ flags) {
    int lane = threadIdx.x & 63;
    unsigned d = xb[lane * 97];
    unsigned ex = (d >> 7) & 0xFFu;              // bf16-packed: low-half bf16 exponent field
    unsigned long long m1 = __ballot(ex >= 110u && ex <= 135u);
    int hi = ei[2 * lane + 1];                   // int64: odd dwords are all zero
    unsigned long long m2 = __ballot(hi == 0);
    if (lane == 0) {
        flags[0] = (__popcll(m1) > 32) ? 0 : 1;  // many bf16-exponent hits -> packed bf16
        flags[1] = (__popcll(m2) > 32) ? 1 : 0;
    }
}

// ---------- K1: merged prep: blocks [0,64) transpose W -> bf16 Wt[128][256]; rest convert x -> bf16 ----------
__global__ void prep(const float4* __restrict__ xf4, uint2* __restrict__ xcvt2,
                     const unsigned* __restrict__ Wsb, const float* __restrict__ Wsf,
                     const unsigned* __restrict__ Wnb, const float* __restrict__ Wnf,
                     unsigned* __restrict__ wt, const int* __restrict__ flags, int n4) {
    if (blockIdx.x < 64) {
        int tid = blockIdx.x * 256 + threadIdx.x;    // 16384 threads: f = tid>>7, k-pair = tid&127
        int f = tid >> 7, k2 = tid & 127;
        int k2l = k2 & 63;
        unsigned out;
        if (flags[0]) {
            const float* W = (k2 < 64) ? Wsf : Wnf;
            float lo = W[(2 * k2l) * 128 + f], hi = W[(2 * k2l + 1) * 128 + f];
            out = f2b(lo) | (f2b(hi) << 16);
        } else {
            const unsigned* W = (k2 < 64) ? Wsb : Wnb;
            unsigned lo = W[(2 * k2l) * 64 + (f >> 1)];
            unsigned hi = W[(2 * k2l + 1) * 64 + (f >> 1)];
            unsigned a = (f & 1) ? (lo >> 16) : (lo & 0xffffu);
            unsigned b = (f & 1) ? (hi & 0xffff0000u) : (hi << 16);
            out = a | b;
        }
        wt[tid] = out;
    } else {
        if (!flags[0]) return;                        // bf16 inputs: no copy needed
        int i = (blockIdx.x - 64) * 256 + threadIdx.x;
        if (i >= n4) return;
        float4 v = xf4[i];
        xcvt2[i] = make_uint2(f2b(v.x) | (f2b(v.y) << 16), f2b(v.z) | (f2b(v.w) << 16));
    }
}

// ---------- K2: per-target degree count + arrival rank + compact int32 tgt (4 edges/thread) ----------
__global__ void edge_count(const int* __restrict__ ei, int* __restrict__ count,
                           int* __restrict__ tgt32, int* __restrict__ rank,
                           const int* __restrict__ flags, int E) {
    int e0 = (blockIdx.x * 256 + threadIdx.x) * 4;
    if (e0 >= E) return;
    int i64 = flags[1];
    if (e0 + 4 <= E) {
        int t0 = eidx(ei, E + e0 + 0, i64), t1 = eidx(ei, E + e0 + 1, i64),
            t2 = eidx(ei, E + e0 + 2, i64), t3 = eidx(ei, E + e0 + 3, i64);
        int r0 = atomicAdd(&count[t0], 1), r1 = atomicAdd(&count[t1], 1),
            r2 = atomicAdd(&count[t2], 1), r3 = atomicAdd(&count[t3], 1);
        *(int4*)(tgt32 + e0) = make_int4(t0, t1, t2, t3);
        *(int4*)(rank + e0)  = make_int4(r0, r1, r2, r3);
    } else {
        for (int j = 0; j < 4 && e0 + j < E; ++j) {
            int t = eidx(ei, E + e0 + j, i64);
            rank[e0 + j] = atomicAdd(&count[t], 1);
            tgt32[e0 + j] = t;
        }
    }
}

// ---------- K3a: multi-block local exclusive scan (4096 elems/block) + block sums ----------
__global__ void scan_blocks(const int* __restrict__ count, int* __restrict__ offsets,
                            int* __restrict__ bsum, int N) {
    __shared__ int wsum[16];
    int tid = threadIdx.x, lane = tid & 63, w = tid >> 6;
    int i0 = blockIdx.x * 4096 + tid * 4;
    int4 v;
    if (i0 + 3 < N) v = *(const int4*)(count + i0);
    else {
        v.x = (i0     < N) ? count[i0]     : 0;
        v.y = (i0 + 1 < N) ? count[i0 + 1] : 0;
        v.z = (i0 + 2 < N) ? count[i0 + 2] : 0;
        v.w = (i0 + 3 < N) ? count[i0 + 3] : 0;
    }
    int s = v.x + v.y + v.z + v.w;
    int incl = s;
    #pragma unroll
    for (int off = 1; off < 64; off <<= 1) {
        int t = __shfl_up(incl, off);
        if (lane >= off) incl += t;
    }
    if (lane == 63) wsum[w] = incl;
    __syncthreads();
    int wpre = 0, tot = 0;
    #pragma unroll
    for (int j = 0; j < 16; ++j) { int sj = wsum[j]; if (j < w) wpre += sj; tot += sj; }
    int o0 = wpre + incl - s;
    int o1 = o0 + v.x, o2 = o1 + v.y, o3 = o2 + v.z;
    if (i0 + 3 < N) {
        *(int4*)(offsets + i0) = make_int4(o0, o1, o2, o3);
    } else {
        if (i0     < N) offsets[i0]     = o0;
        if (i0 + 1 < N) offsets[i0 + 1] = o1;
        if (i0 + 2 < N) offsets[i0 + 2] = o2;
    }
    if (tid == 0) bsum[blockIdx.x] = tot;
}

// ---------- K3b: add block-prefix to each block's offsets; write offsets[N] ----------
__global__ void scan_fixup(int* __restrict__ offsets, const int* __restrict__ bsum,
                           int N, int B) {
    __shared__ int s_pre;
    int b = blockIdx.x;
    if (threadIdx.x == 0) {
        int p = 0;
        for (int j = 0; j < b; ++j) p += bsum[j];
        s_pre = p;
        if (b == B - 1) {
            int tot = p;
            for (int j = b; j < B; ++j) tot += bsum[j];
            offsets[N] = tot;
        }
    }
    __syncthreads();
    int pre = s_pre;
    if (pre == 0) return;                        // block 0: nothing to add
    int i0 = b * 4096 + threadIdx.x * 4;
    if (i0 + 3 < N) {
        int4 t = *(int4*)(offsets + i0);
        t.x += pre; t.y += pre; t.z += pre; t.w += pre;
        *(int4*)(offsets + i0) = t;
    } else {
        for (int j = 0; j < 4; ++j)
            if (i0 + j < N) offsets[i0 + j] += pre;
    }
}

// ---------- K4: atomic-free scatter: pos = offsets[t] + rank[e] (4 edges/thread) ----------
// PACK=1 (N<=65536): 4B record {src:16 | alpha:fp16:16}; else 8B {src, alpha:f32}.
template <int PACK>
__global__ void edge_scatter(const int* __restrict__ ei, const int* __restrict__ tgt32,
                             const int* __restrict__ rank,
                             const float* __restrict__ ewf, const __hip_bfloat16* __restrict__ ewh,
                             const int* __restrict__ offsets, unsigned* __restrict__ csr4,
                             uint2* __restrict__ csr8, const int* __restrict__ flags, int E) {
    int e0 = (blockIdx.x * 256 + threadIdx.x) * 4;
    if (e0 >= E) return;
    int f32 = flags[0], i64 = flags[1];
    if (e0 + 4 <= E) {
        int4 t = *(const int4*)(tgt32 + e0);
        int4 r = *(const int4*)(rank + e0);
        int s0 = eidx(ei, e0 + 0, i64), s1 = eidx(ei, e0 + 1, i64),
            s2 = eidx(ei, e0 + 2, i64), s3 = eidx(ei, e0 + 3, i64);
        float w0 = ldw(ewf, ewh, e0 + 0, f32), w1 = ldw(ewf, ewh, e0 + 1, f32),
              w2 = ldw(ewf, ewh, e0 + 2, f32), w3 = ldw(ewf, ewh, e0 + 3, f32);
        int o0 = offsets[t.x] + r.x, o1 = offsets[t.y] + r.y,
            o2 = offsets[t.z] + r.z, o3 = offsets[t.w] + r.w;
        float a0 = expf(w0), a1 = expf(w1), a2 = expf(w2), a3 = expf(w3);
        if (PACK) {
            csr4[o0] = (unsigned)s0 | ((unsigned)__half_as_ushort(__float2half(a0)) << 16);
            csr4[o1] = (unsigned)s1 | ((unsigned)__half_as_ushort(__float2half(a1)) << 16);
            csr4[o2] = (unsigned)s2 | ((unsigned)__half_as_ushort(__float2half(a2)) << 16);
            csr4[o3] = (unsigned)s3 | ((unsigned)__half_as_ushort(__float2half(a3)) << 16);
        } else {
            csr8[o0] = make_uint2((unsigned)s0, __float_as_uint(a0));
            csr8[o1] = make_uint2((unsigned)s1, __float_as_uint(a1));
            csr8[o2] = make_uint2((unsigned)s2, __float_as_uint(a2));
            csr8[o3] = make_uint2((unsigned)s3, __float_as_uint(a3));
        }
    } else {
        for (int j = 0; j < 4 && e0 + j < E; ++j) {
            int e = e0 + j;
            int t = tgt32[e];
            int s = eidx(ei, e, i64);
            float al = expf(ldw(ewf, ewh, e, f32));
            int pos = offsets[t] + rank[e];
            if (PACK) csr4[pos] = (unsigned)s | ((unsigned)__half_as_ushort(__float2half(al)) << 16);
            else      csr8[pos] = make_uint2((unsigned)s, __float_as_uint(al));
        }
    }
}

// ---------- K5: one wave per target node; 8-deep pipelined gather of bf16 x[src] rows ----------
template <int PACK>
__device__ __forceinline__ void dec_edge(const unsigned* __restrict__ c4,
                                         const uint2* __restrict__ c8, int j,
                                         unsigned& s, float& al) {
    if (PACK) {
        unsigned r = c4[j];
        s = r & 0xffffu;
        al = __half2float(__ushort_as_half((unsigned short)(r >> 16)));
    } else {
        uint2 e = c8[j];
        s = e.x;
        al = __uint_as_float(e.y);
    }
}

template <int PACK>
__global__ void aggregate(const unsigned* __restrict__ xb, const unsigned* __restrict__ xcvt,
                          const int* __restrict__ offsets, const unsigned* __restrict__ csr4,
                          const uint2* __restrict__ csr8, unsigned* __restrict__ aggb,
                          const int* __restrict__ flags, int N) {
    int node = blockIdx.x * 4 + (threadIdx.x >> 6);
    if (node >= N) return;
    int lane = threadIdx.x & 63;
    const unsigned* xs = flags[0] ? xcvt : xb;   // always gather bf16 (half traffic)
    float a0 = 0.f, a1 = 0.f;
    int beg = offsets[node], end = offsets[node + 1];
    int j = beg;
    for (; j + 8 <= end; j += 8) {               // 8 independent gathers in flight
        unsigned s0, s1, s2, s3, s4, s5, s6, s7;
        float l0, l1, l2, l3, l4, l5, l6, l7;
        dec_edge<PACK>(csr4, csr8, j+0, s0, l0); dec_edge<PACK>(csr4, csr8, j+1, s1, l1);
        dec_edge<PACK>(csr4, csr8, j+2, s2, l2); dec_edge<PACK>(csr4, csr8, j+3, s3, l3);
        dec_edge<PACK>(csr4, csr8, j+4, s4, l4); dec_edge<PACK>(csr4, csr8, j+5, s5, l5);
        dec_edge<PACK>(csr4, csr8, j+6, s6, l6); dec_edge<PACK>(csr4, csr8, j+7, s7, l7);
        unsigned p0 = xs[s0 * 64 + lane], p1 = xs[s1 * 64 + lane],
                 p2 = xs[s2 * 64 + lane], p3 = xs[s3 * 64 + lane],
                 p4 = xs[s4 * 64 + lane], p5 = xs[s5 * 64 + lane],
                 p6 = xs[s6 * 64 + lane], p7 = xs[s7 * 64 + lane];
        a0 += l0 * lo16(p0); a1 += l0 * hi16(p0);
        a0 += l1 * lo16(p1); a1 += l1 * hi16(p1);
        a0 += l2 * lo16(p2); a1 += l2 * hi16(p2);
        a0 += l3 * lo16(p3); a1 += l3 * hi16(p3);
        a0 += l4 * lo16(p4); a1 += l4 * hi16(p4);
        a0 += l5 * lo16(p5); a1 += l5 * hi16(p5);
        a0 += l6 * lo16(p6); a1 += l6 * hi16(p6);
        a0 += l7 * lo16(p7); a1 += l7 * hi16(p7);
    }
    for (; j + 4 <= end; j += 4) {
        unsigned s0, s1, s2, s3;
        float l0, l1, l2, l3;
        dec_edge<PACK>(csr4, csr8, j+0, s0, l0); dec_edge<PACK>(csr4, csr8, j+1, s1, l1);
        dec_edge<PACK>(csr4, csr8, j+2, s2, l2); dec_edge<PACK>(csr4, csr8, j+3, s3, l3);
        unsigned p0 = xs[s0 * 64 + lane], p1 = xs[s1 * 64 + lane],
                 p2 = xs[s2 * 64 + lane], p3 = xs[s3 * 64 + lane];
        a0 += l0 * lo16(p0); a1 += l0 * hi16(p0);
        a0 += l1 * lo16(p1); a1 += l1 * hi16(p1);
        a0 += l2 * lo16(p2); a1 += l2 * hi16(p2);
        a0 += l3 * lo16(p3); a1 += l3 * hi16(p3);
    }
    for (; j < end; ++j) {
        unsigned s; float l;
        dec_edge<PACK>(csr4, csr8, j, s, l);
        unsigned p = xs[s * 64 + lane];
        a0 += l * lo16(p); a1 += l * hi16(p);
    }
    float ss = a0 * a0 + a1 * a1;
    #pragma unroll
    for (int m = 32; m >= 1; m >>= 1) ss += __shfl_xor(ss, m);
    float inv = 1.f / (sqrtf(ss) + EPS);
    aggb[node * 64 + lane] = f2b(a0 * inv) | (f2b(a1 * inv) << 16);
}

// ---------- K6: MFMA fused: C = 0.5*([x|agg] @ [Ws;Wn] + bs + bn) -> proj-norm -> LN ----------
// 32 nodes/block, 2 waves x 16 nodes, 16 KB LDS -> ~2x occupancy vs 64-node tile.
// A = [x|agg] bf16 staged in XOR-swizzled LDS; B = Wt[f][k] bf16 from global (L2-resident 64 KB).
// mfma_f32_16x16x32_bf16: C/D: col = lane&15, row = (lane>>4)*4 + reg  [learn_hip m89].
__global__ __launch_bounds__(128) void fused_mfma(
    const unsigned* __restrict__ xb, const unsigned* __restrict__ xcvt,
    const unsigned* __restrict__ aggb, const uint4* __restrict__ wt4,
    const float* __restrict__ bsf, const __hip_bfloat16* __restrict__ bsh,
    const float* __restrict__ bnf, const __hip_bfloat16* __restrict__ bnh,
    const float* __restrict__ gf, const __hip_bfloat16* __restrict__ gh,
    const float* __restrict__ tf, const __hip_bfloat16* __restrict__ th,
    float* __restrict__ outf, unsigned* __restrict__ outb,
    const int* __restrict__ flags, int N)
{
    __shared__ uint4 sA[1024];                   // 32 rows x 32 chunks of 16B = 16 KB
    int f32 = flags[0];
    const uint4* xs4 = (const uint4*)(f32 ? xcvt : xb);
    const uint4* ag4 = (const uint4*)aggb;
    int tid = threadIdx.x;
    int node0 = blockIdx.x * 32;

    // stage A: row r = [x bf16 (chunks 0-15) | agg bf16 (chunks 16-31)], XOR-swizzled
    #pragma unroll
    for (int i = 0; i < 8; ++i) {
        int ci = i * 128 + tid;
        int r = ci >> 5, c = ci & 31;
        int node = node0 + r;
        uint4 v = make_uint4(0, 0, 0, 0);
        if (node < N) v = (c < 16) ? xs4[node * 16 + c] : ag4[node * 16 + (c - 16)];
        sA[r * 32 + (c ^ (r & 15))] = v;
    }
    __syncthreads();

    int lane = tid & 63, w = tid >> 6, g = lane >> 4, c16 = lane & 15;
    int rloc = w * 16 + c16;                     // A row this lane reads

    f32x4 acc[8];
    #pragma unroll
    for (int t = 0; t < 8; ++t) acc[t] = (f32x4){0.f, 0.f, 0.f, 0.f};

    #pragma unroll
    for (int kk = 0; kk < 8; ++kk) {             // K = 256 in steps of 32
        uint4 av = sA[rloc * 32 + ((kk * 4 + g) ^ c16)];
        bf16x8 a = __builtin_bit_cast(bf16x8, av);
        #pragma unroll
        for (int t = 0; t < 8; ++t) {            // 8 feature tiles of 16
            uint4 bv = wt4[(t * 16 + c16) * 32 + kk * 4 + g];
            bf16x8 b = __builtin_bit_cast(bf16x8, bv);
            acc[t] = __builtin_amdgcn_mfma_f32_16x16x32_bf16(a, b, acc[t], 0, 0, 0);
        }
    }

    // per-lane feature params (features f = t*16 + c16)
    float bsum[8], gam[8], bet[8];
    #pragma unroll
    for (int t = 0; t < 8; ++t) {
        int f = t * 16 + c16;
        bsum[t] = ldw(bsf, bsh, f, f32) + ldw(bnf, bnh, f, f32);
        gam[t]  = ldw(gf, gh, f, f32);
        bet[t]  = ldw(tf, th, f, f32);
    }

    // epilogue: per node (4 per lane, one per acc reg), reduce over 16-lane group
    #pragma unroll
    for (int reg = 0; reg < 4; ++reg) {
        int node = node0 + w * 16 + g * 4 + reg;
        float cv[8], s1 = 0.f, s2 = 0.f;
        #pragma unroll
        for (int t = 0; t < 8; ++t) {
            float c_ = 0.5f * (acc[t][reg] + bsum[t]);
            cv[t] = c_; s1 += c_; s2 += c_ * c_;
        }
        #pragma unroll
        for (int m = 1; m < 16; m <<= 1) { s1 += __shfl_xor(s1, m); s2 += __shfl_xor(s2, m); }
        float inv  = 1.f / (sqrtf(s2) + EPS);
        float mean = s1 * inv * (1.f / 128.f);
        float var  = s2 * inv * inv * (1.f / 128.f) - mean * mean;
        float rstd = 1.f / sqrtf(var + LN_EPS);
        if (f32) {
            if (node < N) {
                #pragma unroll
                for (int t = 0; t < 8; ++t) {
                    float o = (cv[t] * inv - mean) * rstd * gam[t] + bet[t];
                    outf[(size_t)node * 128 + t * 16 + c16] = o;
                }
            }
        } else {
            #pragma unroll
            for (int t = 0; t < 8; ++t) {
                float o = (cv[t] * inv - mean) * rstd * gam[t] + bet[t];
                float po = __shfl_xor(o, 1);
                if (!(c16 & 1) && node < N)
                    outb[node * 64 + t * 8 + (c16 >> 1)] = f2b(o) | (f2b(po) << 16);
            }
        }
    }
}

static inline size_t rup16(size_t x) { return (x + 15) & ~(size_t)15; }

extern "C" void kernel_launch(void* const* d_in, const int* in_sizes, int n_in,
                              void* d_out, int out_size, void* d_ws, size_t ws_size,
                              hipStream_t stream) {
    int N = in_sizes[0] / 128;
    int E = in_sizes[1] / 2;
    const int* ei = (const int*)d_in[1];

    char* p = (char*)d_ws;
    int* flags = (int*)p;              p += 16;
    int* count = (int*)p;              p += rup16((size_t)N * 4);
    int* offsets = (int*)p;            p += rup16((size_t)(N + 4) * 4);
    int* bsum = (int*)p;               p += 256;                       // up to 64 block sums
    int* tgt32 = (int*)p;              p += rup16((size_t)E * 4);
    int* rank = (int*)p;               p += rup16((size_t)E * 4);
    unsigned* csr4 = (unsigned*)p;                                     // aliases csr8 region
    uint2* csr8 = (uint2*)p;           p += rup16((size_t)E * 8);
    unsigned* wt = (unsigned*)p;       p += 128 * 128 * 4;             // 64 KB bf16 Wt[128][256]
    unsigned* xcvt = (unsigned*)p;     p += rup16((size_t)N * 64 * 4); // 12.8 MB bf16 x copy
    unsigned* aggb = (unsigned*)p;     // N*64 u32 = 12.8 MB bf16 agg

    // zero flags + count (contiguous at start of ws)
    hipMemsetAsync(d_ws, 0, 16 + (size_t)N * 4, stream);

    int eb4 = (E + 1023) / 1024;
    int nb = (N + 3) / 4;
    int nbf = (N + 31) / 32;
    int ncv = (N * 32 + 255) / 256;
    int scanB = (N + 4095) / 4096;
    int pack = (N <= 65536);

    probe_kernel<<<1, 64, 0, stream>>>((const unsigned*)d_in[0], ei, flags);
    prep<<<64 + ncv, 256, 0, stream>>>((const float4*)d_in[0], (uint2*)xcvt,
                                       (const unsigned*)d_in[3], (const float*)d_in[3],
                                       (const unsigned*)d_in[5], (const float*)d_in[5],
                                       wt, flags, N * 32);
    edge_count<<<eb4, 256, 0, stream>>>(ei, count, tgt32, rank, flags, E);
    scan_blocks<<<scanB, 1024, 0, stream>>>(count, offsets, bsum, N);
    scan_fixup<<<scanB, 1024, 0, stream>>>(offsets, bsum, N, scanB);
    if (pack)
        edge_scatter<1><<<eb4, 256, 0, stream>>>(ei, tgt32, rank, (const float*)d_in[2],
                                                 (const __hip_bfloat16*)d_in[2],
                                                 offsets, csr4, csr8, flags, E);
    else
        edge_scatter<0><<<eb4, 256, 0, stream>>>(ei, tgt32, rank, (const float*)d_in[2],
                                                 (const __hip_bfloat16*)d_in[2],
                                                 offsets, csr4, csr8, flags, E);
    if (pack)
        aggregate<1><<<nb, 256, 0, stream>>>((const unsigned*)d_in[0], xcvt,
                                             offsets, csr4, csr8, aggb, flags, N);
    else
        aggregate<0><<<nb, 256, 0, stream>>>((const unsigned*)d_in[0], xcvt,
                                             offsets, csr4, csr8, aggb, flags, N);
    fused_mfma<<<nbf, 128, 0, stream>>>((const unsigned*)d_in[0], xcvt, aggb, (const uint4*)wt,
                                        (const float*)d_in[4], (const __hip_bfloat16*)d_in[4],
                                        (const float*)d_in[6], (const __hip_bfloat16*)d_in[6],
                                        (const float*)d_in[7], (const __hip_bfloat16*)d_in[7],
                                        (const float*)d_in[8], (const __hip_bfloat16*)d_in[8],
                                        (float*)d_out, (unsigned*)d_out, flags, N);
}